// Round 4
// baseline (263.062 us; speedup 1.0000x reference)
//
#include <hip/hip_runtime.h>
#include <hip/hip_bf16.h>
#include <stdint.h>

#define N_NODES 50000
#define N_EDGES 800000
#define D 128          // D_IN == D_OUT
#define NB_SCAN 196    // ceil(50000/256)

typedef __attribute__((ext_vector_type(8))) short bf16x8;
typedef __attribute__((ext_vector_type(4))) float f32x4;
typedef __attribute__((ext_vector_type(2))) short bf16x2;

// ---- workspace layout (bytes) ----
#define FEATBF_OFF 0                      // N_NODES*128 bf16 = 12,800,000
#define MEANBF_OFF 12800000               // N_NODES*128 bf16 = 12,800,000
#define WSW_OFF    25600000               // swizzled bf16 W   =     65,536
#define HIST_OFF   25665536               // N_NODES i32       =    200,000 (memset 0)
#define OFFS_OFF   25865536               // (N_NODES+1) i32
#define CURS_OFF   26065552               // N_NODES i32
#define EDGE_OFF   26265552               // N_EDGES u32 packed (src<<16 | bf16 w) = 3,200,000
#define BSUM_OFF   29465552               // NB_SCAN i32
#define BOFF_OFF   29466576               // NB_SCAN i32
// total ~29.5 MB

__device__ inline short f2bf(float x) {
  union { float f; uint32_t u; } v; v.f = x;
  uint32_t r = v.u + 0x7FFFu + ((v.u >> 16) & 1u);   // RNE
  return (short)(r >> 16);
}
__device__ inline float bf2f(uint32_t bits16) {
  union { uint32_t u; float f; } v; v.u = bits16 << 16;
  return v.f;
}

// prep: [0,3125) feature f32->bf16 ; [3125,6250) degree hist ; [6250,6266) W swizzle
__global__ __launch_bounds__(256) void k_prep(const float* __restrict__ feat,
                                              const int* __restrict__ idx,
                                              const float* __restrict__ W,
                                              short* __restrict__ featbf,
                                              int* __restrict__ hist,
                                              short* __restrict__ wsw) {
  int b = blockIdx.x;
  if (b < 3125) {                                    // feature convert: 8 elems/thread
    int i = (b * 256 + threadIdx.x) * 8;             // covers 6,400,000 exactly
    f32x4 a0 = *(const f32x4*)(feat + i);
    f32x4 a1 = *(const f32x4*)(feat + i + 4);
    bf16x8 o;
    o[0] = f2bf(a0.x); o[1] = f2bf(a0.y); o[2] = f2bf(a0.z); o[3] = f2bf(a0.w);
    o[4] = f2bf(a1.x); o[5] = f2bf(a1.y); o[6] = f2bf(a1.z); o[7] = f2bf(a1.w);
    *(bf16x8*)(featbf + i) = o;
  } else if (b < 6250) {                             // hist: 800,000 edges exactly
    int e = (b - 3125) * 256 + threadIdx.x;
    atomicAdd(&hist[idx[e]], 1);
  } else {                                           // W swizzle (16 blocks)
    int t = (b - 6250) * 256 + threadIdx.x;          // 0..4095
    int kstep = t >> 9;
    int ntile = (t >> 6) & 7;
    int lane  = t & 63;
    int k0  = kstep * 32 + (lane >> 4) * 8;
    int col = ntile * 16 + (lane & 15);
    bf16x8 o;
    #pragma unroll
    for (int j = 0; j < 8; ++j) o[j] = f2bf(W[(k0 + j) * D + col]);
    *(bf16x8*)(wsw + t * 8) = o;
  }
}

// scan 1/2/3: two-level exclusive prefix sum of hist -> offs, cursor
__global__ __launch_bounds__(256) void k_scan1(const int* __restrict__ hist,
                                               int* __restrict__ blockSum) {
  __shared__ int red[256];
  int t = threadIdx.x;
  int i = blockIdx.x * 256 + t;
  red[t] = (i < N_NODES) ? hist[i] : 0;
  __syncthreads();
  #pragma unroll
  for (int s = 128; s > 0; s >>= 1) {
    if (t < s) red[t] += red[t + s];
    __syncthreads();
  }
  if (t == 0) blockSum[blockIdx.x] = red[0];
}

__global__ __launch_bounds__(256) void k_scan2(const int* __restrict__ blockSum,
                                               int* __restrict__ blockOff,
                                               int* __restrict__ offs) {
  __shared__ int lds[256];
  int t = threadIdx.x;
  int v = (t < NB_SCAN) ? blockSum[t] : 0;
  lds[t] = v;
  __syncthreads();
  #pragma unroll
  for (int off = 1; off < 256; off <<= 1) {
    int add = (t >= off) ? lds[t - off] : 0;
    __syncthreads();
    lds[t] += add;
    __syncthreads();
  }
  if (t < NB_SCAN) blockOff[t] = lds[t] - v;
  if (t == 255) offs[N_NODES] = lds[255];
}

__global__ __launch_bounds__(256) void k_scan3(const int* __restrict__ hist,
                                               const int* __restrict__ blockOff,
                                               int* __restrict__ offs,
                                               int* __restrict__ cursor) {
  __shared__ int lds[256];
  int t = threadIdx.x;
  int i = blockIdx.x * 256 + t;
  int v = (i < N_NODES) ? hist[i] : 0;
  lds[t] = v;
  __syncthreads();
  #pragma unroll
  for (int off = 1; off < 256; off <<= 1) {
    int add = (t >= off) ? lds[t - off] : 0;
    __syncthreads();
    lds[t] += add;
    __syncthreads();
  }
  int excl = lds[t] - v + blockOff[blockIdx.x];
  if (i < N_NODES) { offs[i] = excl; cursor[i] = excl; }
}

// scatter edges into CSR as packed u32 = (src16 << 16) | bf16(w)
__global__ __launch_bounds__(256) void k_scatter(const int* __restrict__ idx,
                                                 const float* __restrict__ w,
                                                 int* __restrict__ cursor,
                                                 uint32_t* __restrict__ edge) {
  int e = blockIdx.x * 256 + threadIdx.x;
  if (e < N_EDGES) {
    int dst = idx[e];
    int p = atomicAdd(&cursor[dst], 1);
    uint32_t src = (uint32_t)idx[N_EDGES + e];
    uint32_t wb  = (uint32_t)f2bf(w[e]) & 0xFFFFu;
    edge[p] = (src << 16) | wb;
  }
}

// per-node aggregation: 64 lanes per node, bf16 gather, writes bf16 mean
__global__ __launch_bounds__(256) void k_agg(const short* __restrict__ featbf,
                                             const int* __restrict__ offs,
                                             const uint32_t* __restrict__ edge,
                                             short* __restrict__ meanbf) {
  int t = blockIdx.x * 256 + threadIdx.x;
  int node = t >> 6;
  int c = t & 63;                  // lane covers cols 2c, 2c+1
  if (node >= N_NODES) return;
  int beg = offs[node], end = offs[node + 1];
  float a0 = 0.f, a1 = 0.f;
  for (int j = beg; j < end; ++j) {
    uint32_t ed = edge[j];
    float wt = bf2f(ed & 0xFFFFu);
    uint32_t src = ed >> 16;
    bf16x2 f = *(const bf16x2*)(featbf + (size_t)src * D + c * 2);
    a0 += bf2f((uint16_t)f[0]) * wt;
    a1 += bf2f((uint16_t)f[1]) * wt;
  }
  float invc = 1.0f / fmaxf((float)(end - beg), 1.0f);
  bf16x2 o;
  o[0] = f2bf(a0 * invc);
  o[1] = f2bf(a1 * invc);
  *(bf16x2*)(meanbf + (size_t)node * D + c * 2) = o;
}

// fused GEMM: out = featbf @ W0 + meanbf @ W1 + b.  A-frags direct 16B loads, no LDS.
__global__ __launch_bounds__(256) void k_gemm(const short* __restrict__ featbf,
                                              const short* __restrict__ meanbf,
                                              const short* __restrict__ wsw,
                                              const float* __restrict__ bias,
                                              float* __restrict__ out) {
  int wave = threadIdx.x >> 6;
  int lane = threadIdx.x & 63;
  int waveId = blockIdx.x * 4 + wave;
  int R = waveId * 16;
  if (R >= N_NODES) return;

  int row_l = lane & 15;
  int kq    = lane >> 4;
  int myrow = R + row_l;

  f32x4 acc[8];
  #pragma unroll
  for (int nt = 0; nt < 8; ++nt) acc[nt] = (f32x4){0.f, 0.f, 0.f, 0.f};

  #pragma unroll
  for (int kstep = 0; kstep < 8; ++kstep) {
    int kbase = (kstep & 3) * 32 + kq * 8;
    const short* srcrow = (kstep < 4) ? (featbf + (size_t)myrow * D + kbase)
                                      : (meanbf + (size_t)myrow * D + kbase);
    bf16x8 af = *(const bf16x8*)srcrow;
    const bf16x8* wrow = (const bf16x8*)(wsw + ((size_t)kstep * 8 * 64 + lane) * 8);
    #pragma unroll
    for (int nt = 0; nt < 8; ++nt) {
      bf16x8 bf = wrow[nt * 64];
      acc[nt] = __builtin_amdgcn_mfma_f32_16x16x32_bf16(af, bf, acc[nt], 0, 0, 0);
    }
  }

  // C/D layout: col = lane&15, row = (lane>>4)*4 + reg
  #pragma unroll
  for (int nt = 0; nt < 8; ++nt) {
    int col = nt * 16 + row_l;
    float bv = bias[col];
    #pragma unroll
    for (int r = 0; r < 4; ++r) {
      int orow = R + kq * 4 + r;
      out[(size_t)orow * D + col] = acc[nt][r] + bv;
    }
  }
}

extern "C" void kernel_launch(void* const* d_in, const int* in_sizes, int n_in,
                              void* d_out, int out_size, void* d_ws, size_t ws_size,
                              hipStream_t stream) {
  const float* feature = (const float*)d_in[0];
  const int*   rel_idx = (const int*)d_in[1];
  const float* rel_w   = (const float*)d_in[2];
  const float* W       = (const float*)d_in[3];
  const float* b       = (const float*)d_in[4];
  float* out = (float*)d_out;

  char* ws = (char*)d_ws;
  short*    featbf = (short*)(ws + FEATBF_OFF);
  short*    meanbf = (short*)(ws + MEANBF_OFF);
  short*    wsw    = (short*)(ws + WSW_OFF);
  int*      hist   = (int*)(ws + HIST_OFF);
  int*      offs   = (int*)(ws + OFFS_OFF);
  int*      curs   = (int*)(ws + CURS_OFF);
  uint32_t* edge   = (uint32_t*)(ws + EDGE_OFF);
  int*      bsum   = (int*)(ws + BSUM_OFF);
  int*      boff   = (int*)(ws + BOFF_OFF);

  hipMemsetAsync(hist, 0, N_NODES * sizeof(int), stream);
  k_prep<<<6266, 256, 0, stream>>>(feature, rel_idx, W, featbf, hist, wsw);
  k_scan1<<<NB_SCAN, 256, 0, stream>>>(hist, bsum);
  k_scan2<<<1, 256, 0, stream>>>(bsum, boff, offs);
  k_scan3<<<NB_SCAN, 256, 0, stream>>>(hist, boff, offs, curs);
  k_scatter<<<(N_EDGES + 255) / 256, 256, 0, stream>>>(rel_idx, rel_w, curs, edge);
  k_agg<<<(N_NODES * 64 + 255) / 256, 256, 0, stream>>>(featbf, offs, edge, meanbf);
  int gemmBlocks = (N_NODES / 16 + 3) / 4;
  k_gemm<<<gemmBlocks, 256, 0, stream>>>(featbf, meanbf, wsw, b, out);
}

// Round 5
// 229.604 us; speedup vs baseline: 1.1457x; 1.1457x over previous
//
#include <hip/hip_runtime.h>
#include <hip/hip_bf16.h>
#include <stdint.h>

#define N_NODES 50000
#define N_EDGES 800000
#define D 128          // D_IN == D_OUT
#define NB_SCAN 196    // ceil(50000/256)

typedef __attribute__((ext_vector_type(8))) short bf16x8;
typedef __attribute__((ext_vector_type(4))) float f32x4;
typedef __attribute__((ext_vector_type(2))) short bf16x2;

// ---- workspace layout (bytes) ----
#define FEATBF_OFF 0                      // N_NODES*128 bf16 = 12,800,000
#define MEANBF_OFF 12800000               // N_NODES*128 bf16 = 12,800,000
#define WSW_OFF    25600000               // swizzled bf16 W   =     65,536
#define HIST_OFF   25665536               // N_NODES i32       =    200,000 (memset 0)
#define OFFS_OFF   25865536               // (N_NODES+1) i32
#define CURS_OFF   26065552               // N_NODES i32
#define EDGE_OFF   26265552               // N_EDGES u32 packed (src<<16 | bf16 w) = 3,200,000
#define BSUM_OFF   29465552               // NB_SCAN i32
#define BOFF_OFF   29466576               // NB_SCAN i32

__device__ inline short f2bf(float x) {
  union { float f; uint32_t u; } v; v.f = x;
  uint32_t r = v.u + 0x7FFFu + ((v.u >> 16) & 1u);   // RNE
  return (short)(r >> 16);
}
__device__ inline float bf2f(uint32_t bits16) {
  union { uint32_t u; float f; } v; v.u = bits16 << 16;
  return v.f;
}

// prep: [0,3125) feature f32->bf16 ; [3125,6250) degree hist ; [6250,6266) W swizzle
__global__ __launch_bounds__(256) void k_prep(const float* __restrict__ feat,
                                              const int* __restrict__ idx,
                                              const float* __restrict__ W,
                                              short* __restrict__ featbf,
                                              int* __restrict__ hist,
                                              short* __restrict__ wsw) {
  int b = blockIdx.x;
  if (b < 3125) {                                    // feature convert: 8 elems/thread
    int i = (b * 256 + threadIdx.x) * 8;             // covers 6,400,000 exactly
    f32x4 a0 = *(const f32x4*)(feat + i);
    f32x4 a1 = *(const f32x4*)(feat + i + 4);
    bf16x8 o;
    o[0] = f2bf(a0.x); o[1] = f2bf(a0.y); o[2] = f2bf(a0.z); o[3] = f2bf(a0.w);
    o[4] = f2bf(a1.x); o[5] = f2bf(a1.y); o[6] = f2bf(a1.z); o[7] = f2bf(a1.w);
    *(bf16x8*)(featbf + i) = o;
  } else if (b < 6250) {                             // hist: 800,000 edges exactly
    int e = (b - 3125) * 256 + threadIdx.x;
    atomicAdd(&hist[idx[e]], 1);
  } else {                                           // W swizzle (16 blocks)
    int t = (b - 6250) * 256 + threadIdx.x;          // 0..4095
    int kstep = t >> 9;
    int ntile = (t >> 6) & 7;
    int lane  = t & 63;
    int k0  = kstep * 32 + (lane >> 4) * 8;
    int col = ntile * 16 + (lane & 15);
    bf16x8 o;
    #pragma unroll
    for (int j = 0; j < 8; ++j) o[j] = f2bf(W[(k0 + j) * D + col]);
    *(bf16x8*)(wsw + t * 8) = o;
  }
}

// scan 1/2/3: two-level exclusive prefix sum of hist -> offs, cursor
__global__ __launch_bounds__(256) void k_scan1(const int* __restrict__ hist,
                                               int* __restrict__ blockSum) {
  __shared__ int red[256];
  int t = threadIdx.x;
  int i = blockIdx.x * 256 + t;
  red[t] = (i < N_NODES) ? hist[i] : 0;
  __syncthreads();
  #pragma unroll
  for (int s = 128; s > 0; s >>= 1) {
    if (t < s) red[t] += red[t + s];
    __syncthreads();
  }
  if (t == 0) blockSum[blockIdx.x] = red[0];
}

__global__ __launch_bounds__(256) void k_scan2(const int* __restrict__ blockSum,
                                               int* __restrict__ blockOff,
                                               int* __restrict__ offs) {
  __shared__ int lds[256];
  int t = threadIdx.x;
  int v = (t < NB_SCAN) ? blockSum[t] : 0;
  lds[t] = v;
  __syncthreads();
  #pragma unroll
  for (int off = 1; off < 256; off <<= 1) {
    int add = (t >= off) ? lds[t - off] : 0;
    __syncthreads();
    lds[t] += add;
    __syncthreads();
  }
  if (t < NB_SCAN) blockOff[t] = lds[t] - v;
  if (t == 255) offs[N_NODES] = lds[255];
}

__global__ __launch_bounds__(256) void k_scan3(const int* __restrict__ hist,
                                               const int* __restrict__ blockOff,
                                               int* __restrict__ offs,
                                               int* __restrict__ cursor) {
  __shared__ int lds[256];
  int t = threadIdx.x;
  int i = blockIdx.x * 256 + t;
  int v = (i < N_NODES) ? hist[i] : 0;
  lds[t] = v;
  __syncthreads();
  #pragma unroll
  for (int off = 1; off < 256; off <<= 1) {
    int add = (t >= off) ? lds[t - off] : 0;
    __syncthreads();
    lds[t] += add;
    __syncthreads();
  }
  int excl = lds[t] - v + blockOff[blockIdx.x];
  if (i < N_NODES) { offs[i] = excl; cursor[i] = excl; }
}

// scatter edges into CSR as packed u32 = (src16 << 16) | bf16(w)
__global__ __launch_bounds__(256) void k_scatter(const int* __restrict__ idx,
                                                 const float* __restrict__ w,
                                                 int* __restrict__ cursor,
                                                 uint32_t* __restrict__ edge) {
  int e = blockIdx.x * 256 + threadIdx.x;
  if (e < N_EDGES) {
    int dst = idx[e];
    int p = atomicAdd(&cursor[dst], 1);
    uint32_t src = (uint32_t)idx[N_EDGES + e];
    uint32_t wb  = (uint32_t)f2bf(w[e]) & 0xFFFFu;
    edge[p] = (src << 16) | wb;
  }
}

// per-node aggregation: 64 lanes/node, unroll-4 edges with independent
// accumulator pairs -> 4 gathers in flight per lane (latency hiding).
__global__ __launch_bounds__(256) void k_agg(const short* __restrict__ featbf,
                                             const int* __restrict__ offs,
                                             const uint32_t* __restrict__ edge,
                                             short* __restrict__ meanbf) {
  int t = blockIdx.x * 256 + threadIdx.x;
  int node = t >> 6;
  int c = t & 63;                  // lane covers cols 2c, 2c+1
  if (node >= N_NODES) return;
  int beg = offs[node], end = offs[node + 1];

  float a0 = 0.f, a1 = 0.f, b0 = 0.f, b1 = 0.f;
  float c0 = 0.f, c1 = 0.f, d0 = 0.f, d1 = 0.f;

  int j = beg;
  for (; j + 3 < end; j += 4) {
    uint32_t e0 = edge[j + 0];
    uint32_t e1 = edge[j + 1];
    uint32_t e2 = edge[j + 2];
    uint32_t e3 = edge[j + 3];
    bf16x2 f0 = *(const bf16x2*)(featbf + (size_t)(e0 >> 16) * D + c * 2);
    bf16x2 f1 = *(const bf16x2*)(featbf + (size_t)(e1 >> 16) * D + c * 2);
    bf16x2 f2 = *(const bf16x2*)(featbf + (size_t)(e2 >> 16) * D + c * 2);
    bf16x2 f3 = *(const bf16x2*)(featbf + (size_t)(e3 >> 16) * D + c * 2);
    float w0 = bf2f(e0 & 0xFFFFu), w1 = bf2f(e1 & 0xFFFFu);
    float w2 = bf2f(e2 & 0xFFFFu), w3 = bf2f(e3 & 0xFFFFu);
    a0 += bf2f((uint16_t)f0[0]) * w0;  a1 += bf2f((uint16_t)f0[1]) * w0;
    b0 += bf2f((uint16_t)f1[0]) * w1;  b1 += bf2f((uint16_t)f1[1]) * w1;
    c0 += bf2f((uint16_t)f2[0]) * w2;  c1 += bf2f((uint16_t)f2[1]) * w2;
    d0 += bf2f((uint16_t)f3[0]) * w3;  d1 += bf2f((uint16_t)f3[1]) * w3;
  }
  for (; j < end; ++j) {
    uint32_t ed = edge[j];
    float wt = bf2f(ed & 0xFFFFu);
    bf16x2 f = *(const bf16x2*)(featbf + (size_t)(ed >> 16) * D + c * 2);
    a0 += bf2f((uint16_t)f[0]) * wt;
    a1 += bf2f((uint16_t)f[1]) * wt;
  }
  float s0 = (a0 + b0) + (c0 + d0);
  float s1 = (a1 + b1) + (c1 + d1);

  float invc = 1.0f / fmaxf((float)(end - beg), 1.0f);
  bf16x2 o;
  o[0] = f2bf(s0 * invc);
  o[1] = f2bf(s1 * invc);
  *(bf16x2*)(meanbf + (size_t)node * D + c * 2) = o;
}

// fused GEMM: out = featbf @ W0 + meanbf @ W1 + b.  A-frags direct 16B loads, no LDS.
__global__ __launch_bounds__(256) void k_gemm(const short* __restrict__ featbf,
                                              const short* __restrict__ meanbf,
                                              const short* __restrict__ wsw,
                                              const float* __restrict__ bias,
                                              float* __restrict__ out) {
  int wave = threadIdx.x >> 6;
  int lane = threadIdx.x & 63;
  int waveId = blockIdx.x * 4 + wave;
  int R = waveId * 16;
  if (R >= N_NODES) return;

  int row_l = lane & 15;
  int kq    = lane >> 4;
  int myrow = R + row_l;

  f32x4 acc[8];
  #pragma unroll
  for (int nt = 0; nt < 8; ++nt) acc[nt] = (f32x4){0.f, 0.f, 0.f, 0.f};

  #pragma unroll
  for (int kstep = 0; kstep < 8; ++kstep) {
    int kbase = (kstep & 3) * 32 + kq * 8;
    const short* srcrow = (kstep < 4) ? (featbf + (size_t)myrow * D + kbase)
                                      : (meanbf + (size_t)myrow * D + kbase);
    bf16x8 af = *(const bf16x8*)srcrow;
    const bf16x8* wrow = (const bf16x8*)(wsw + ((size_t)kstep * 8 * 64 + lane) * 8);
    #pragma unroll
    for (int nt = 0; nt < 8; ++nt) {
      bf16x8 bf = wrow[nt * 64];
      acc[nt] = __builtin_amdgcn_mfma_f32_16x16x32_bf16(af, bf, acc[nt], 0, 0, 0);
    }
  }

  // C/D layout: col = lane&15, row = (lane>>4)*4 + reg
  #pragma unroll
  for (int nt = 0; nt < 8; ++nt) {
    int col = nt * 16 + row_l;
    float bv = bias[col];
    #pragma unroll
    for (int r = 0; r < 4; ++r) {
      int orow = R + kq * 4 + r;
      out[(size_t)orow * D + col] = acc[nt][r] + bv;
    }
  }
}

extern "C" void kernel_launch(void* const* d_in, const int* in_sizes, int n_in,
                              void* d_out, int out_size, void* d_ws, size_t ws_size,
                              hipStream_t stream) {
  const float* feature = (const float*)d_in[0];
  const int*   rel_idx = (const int*)d_in[1];
  const float* rel_w   = (const float*)d_in[2];
  const float* W       = (const float*)d_in[3];
  const float* b       = (const float*)d_in[4];
  float* out = (float*)d_out;

  char* ws = (char*)d_ws;
  short*    featbf = (short*)(ws + FEATBF_OFF);
  short*    meanbf = (short*)(ws + MEANBF_OFF);
  short*    wsw    = (short*)(ws + WSW_OFF);
  int*      hist   = (int*)(ws + HIST_OFF);
  int*      offs   = (int*)(ws + OFFS_OFF);
  int*      curs   = (int*)(ws + CURS_OFF);
  uint32_t* edge   = (uint32_t*)(ws + EDGE_OFF);
  int*      bsum   = (int*)(ws + BSUM_OFF);
  int*      boff   = (int*)(ws + BOFF_OFF);

  hipMemsetAsync(hist, 0, N_NODES * sizeof(int), stream);
  k_prep<<<6266, 256, 0, stream>>>(feature, rel_idx, W, featbf, hist, wsw);
  k_scan1<<<NB_SCAN, 256, 0, stream>>>(hist, bsum);
  k_scan2<<<1, 256, 0, stream>>>(bsum, boff, offs);
  k_scan3<<<NB_SCAN, 256, 0, stream>>>(hist, boff, offs, curs);
  k_scatter<<<(N_EDGES + 255) / 256, 256, 0, stream>>>(rel_idx, rel_w, curs, edge);
  k_agg<<<(N_NODES * 64 + 255) / 256, 256, 0, stream>>>(featbf, offs, edge, meanbf);
  int gemmBlocks = (N_NODES / 16 + 3) / 4;
  k_gemm<<<gemmBlocks, 256, 0, stream>>>(featbf, meanbf, wsw, b, out);
}